// Round 1
// baseline (988.881 us; speedup 1.0000x reference)
//
#include <hip/hip_runtime.h>
#include <hip/hip_fp16.h>
#include <cstdint>

#define DEV static __device__ __forceinline__

typedef _Float16 f16x2 __attribute__((ext_vector_type(2)));

DEV float fdot2u(uint32_t a, uint32_t b, float c){
  union U { uint32_t u; f16x2 h; };
  U ua; ua.u = a; U ub; ub.u = b;
#if __has_builtin(__builtin_amdgcn_fdot2)
  return __builtin_amdgcn_fdot2(ua.h, ub.h, c, false);
#else
  return c + (float)ua.h[0]*(float)ub.h[0] + (float)ua.h[1]*(float)ub.h[1];
#endif
}

DEV float wsum64(float v){
  #pragma unroll
  for (int o = 32; o; o >>= 1) v += __shfl_xor(v, o);
  return v;
}

DEV float block_sum256(float v, float* red){
  v = wsum64(v);
  int w = threadIdx.x >> 6;
  __syncthreads();
  if ((threadIdx.x & 63) == 0) red[w] = v;
  __syncthreads();
  return red[0] + red[1] + red[2] + red[3];
}

DEV uint32_t pack2h(float a, float b){
  __half ha = __float2half(a), hb = __float2half(b);
  return (uint32_t)__half_as_ushort(ha) | ((uint32_t)__half_as_ushort(hb) << 16);
}

// ---------------- weight transposes (once per call) ----------------
__global__ __launch_bounds__(256) void k_tr(
  const float* __restrict__ wq, const float* __restrict__ wv,
  const float* __restrict__ wih, const float* __restrict__ whh,
  const float* __restrict__ w1, const float* __restrict__ w2,
  float* __restrict__ wqT, float* __restrict__ wvT,
  float* __restrict__ wihT, float* __restrict__ whhT,
  float* __restrict__ w1T, float* __restrict__ w2T)
{
  int gid = blockIdx.x * 256 + threadIdx.x;
  if (gid < 65536){ int e = gid >> 8, d = gid & 255; wqT[gid] = wq[d*256 + e]; }
  else if (gid < 131072){ int g2 = gid - 65536; int e = g2 >> 8, d = g2 & 255; wvT[g2] = wv[d*256 + e]; }
  else if (gid < 327680){ int g2 = gid - 131072; int e = g2 / 768, j = g2 - e*768; wihT[g2] = wih[j*256 + e]; }
  else if (gid < 524288){ int g2 = gid - 327680; int e = g2 / 768, j = g2 - e*768; whhT[g2] = whh[j*256 + e]; }
  else if (gid < 655360){ int g2 = gid - 524288; int e = g2 >> 9, j = g2 & 511; w1T[g2] = w1[j*256 + e]; }
  else { int g2 = gid - 655360; int e2 = g2 >> 8, d = g2 & 255; w2T[g2] = w2[d*512 + e2]; }
}

// ---------------- input LayerNorm -> x_hat (f16 pairs) ----------------
template<bool WX>
__global__ __launch_bounds__(256) void k_ln(
  const float* __restrict__ xin, const float* __restrict__ g,
  const float* __restrict__ b, uint32_t* __restrict__ xhat,
  float* __restrict__ rowstats)
{
  int row = blockIdx.x * 4 + (threadIdx.x >> 6);
  int lane = threadIdx.x & 63;
  const float4 xv = ((const float4*)(xin + (size_t)row * 256))[lane];
  float s1 = wsum64(xv.x + xv.y + xv.z + xv.w);
  float s2 = wsum64(xv.x*xv.x + xv.y*xv.y + xv.z*xv.z + xv.w*xv.w);
  float m = s1 * (1.0f/256.0f);
  float var = s2 * (1.0f/256.0f) - m*m;
  float rstd = rsqrtf(var + 1e-5f);
  if (lane == 0) ((float2*)rowstats)[row] = make_float2(m, rstd);
  if (WX){
    float4 gv = ((const float4*)g)[lane];
    float4 bv = ((const float4*)b)[lane];
    float y0 = (xv.x - m)*rstd*gv.x + bv.x;
    float y1 = (xv.y - m)*rstd*gv.y + bv.y;
    float y2 = (xv.z - m)*rstd*gv.z + bv.z;
    float y3 = (xv.w - m)*rstd*gv.w + bv.w;
    ((uint2*)(xhat + (size_t)row * 128))[lane] = make_uint2(pack2h(y0,y1), pack2h(y2,y3));
  }
}

// ---------------- slot init ----------------
__global__ __launch_bounds__(256) void k_init(
  const float* __restrict__ noise, const float* __restrict__ mu,
  const float* __restrict__ sig, float* __restrict__ S0)
{
  int i = blockIdx.x * 256 + threadIdx.x;
  int d = i & 255;
  float x = sig[d];
  float sp = (x > 20.0f) ? x : log1pf(__expf(x));
  S0[i] = mu[d] + sp * noise[i];
}

// ---------------- per-iter: q = LN_s(slots)@wqT+bq; c=bk.q; qt = wk^T q (packed f16); zero accumulators ----------------
__global__ __launch_bounds__(256) void k_qqt(
  const float* __restrict__ slots, const float* __restrict__ lsg,
  const float* __restrict__ lsb, const float* __restrict__ wqT,
  const float* __restrict__ bq, const float* __restrict__ wk,
  const float* __restrict__ bk, uint32_t* __restrict__ qtpk,
  float* __restrict__ cvec, float* __restrict__ uacc,
  float* __restrict__ asum)
{
  __shared__ float sn[256];
  __shared__ float ql[256];
  __shared__ float red[4];
  int r = blockIdx.x, t = threadIdx.x;
  float x = slots[r*256 + t];
  float s1 = block_sum256(x, red);
  float s2 = block_sum256(x*x, red);
  float m = s1 * (1.0f/256.0f);
  float var = s2 * (1.0f/256.0f) - m*m;
  float rstd = rsqrtf(var + 1e-5f);
  sn[t] = (x - m)*rstd*lsg[t] + lsb[t];
  uacc[r*256 + t] = 0.0f;
  if (t == 0) asum[r] = 0.0f;
  __syncthreads();
  float qa = bq[t];
  #pragma unroll 4
  for (int e = 0; e < 256; ++e) qa += sn[e] * wqT[e*256 + t];
  ql[t] = qa;
  __syncthreads();
  float ct = block_sum256(bk[t]*qa, red);
  float qt = 0.0f;
  #pragma unroll 4
  for (int d = 0; d < 256; ++d) qt += ql[d] * wk[d*256 + t];
  __syncthreads();
  sn[t] = qt;
  if (t == 0) cvec[r] = ct;
  __syncthreads();
  if (t < 128){
    uint32_t p = pack2h(sn[2*t], sn[2*t+1]);
    qtpk[(r >> 3)*1024 + t*8 + (r & 7)] = p;   // [b][dp][s]
  }
}

// ---------------- per-iter fused attention pass ----------------
// grid (16,32): chunk, b. 256 rows/block in 4 subtiles of 64.
template<bool XF16, bool LAST>
__global__ __launch_bounds__(256) void k_attn(
  const uint32_t* __restrict__ xhat, const float* __restrict__ xin,
  const float* __restrict__ rowstats,
  const float* __restrict__ gin, const float* __restrict__ bin,
  const uint32_t* __restrict__ qtpk, const float* __restrict__ cvec,
  float* __restrict__ uacc, float* __restrict__ asum,
  float* __restrict__ attn_out)
{
  __shared__ uint32_t xs[64*135];   // 64 rows x 128 f16-pairs, stride 135 dwords (bank-safe)
  __shared__ float lg[64*12];       // logits / attn, stride 12
  __shared__ uint32_t qs[1024];     // q-tilde packed [dp][8]
  __shared__ float cs[8];
  const int b = blockIdx.y, chunk = blockIdx.x;
  const int t = threadIdx.x;
  const int lane = t & 63, w = t >> 6;
  for (int i = t; i < 1024; i += 256) qs[i] = qtpk[b*1024 + i];
  if (t < 8) cs[t] = cvec[b*8 + t];
  float up[8] = {0,0,0,0,0,0,0,0};
  float asl[8] = {0,0,0,0,0,0,0,0};
  const int shf = (t & 1) * 16;
  for (int st = 0; st < 4; ++st){
    const int gr0 = b*4096 + chunk*256 + st*64;
    __syncthreads();
    if (XF16){
      #pragma unroll
      for (int k = 0; k < 8; ++k){
        int c4 = k*256 + t;
        int row = c4 >> 5, j = c4 & 31;
        uint4 dv = ((const uint4*)xhat)[(size_t)(gr0 + row)*32 + j];
        uint32_t* dst = xs + row*135 + j*4;
        dst[0] = dv.x; dst[1] = dv.y; dst[2] = dv.z; dst[3] = dv.w;
      }
    } else {
      #pragma unroll
      for (int k = 0; k < 16; ++k){
        int c4 = k*256 + t;
        int row = c4 >> 6, j = c4 & 63;
        float4 xv = ((const float4*)(xin + (size_t)(gr0 + row)*256))[j];
        float2 stt = ((const float2*)rowstats)[gr0 + row];
        float4 gv = ((const float4*)gin)[j];
        float4 bv = ((const float4*)bin)[j];
        float y0 = (xv.x - stt.x)*stt.y*gv.x + bv.x;
        float y1 = (xv.y - stt.x)*stt.y*gv.y + bv.y;
        float y2 = (xv.z - stt.x)*stt.y*gv.z + bv.z;
        float y3 = (xv.w - stt.x)*stt.y*gv.w + bv.w;
        uint32_t* dst = xs + row*135 + j*2;
        dst[0] = pack2h(y0, y1); dst[1] = pack2h(y2, y3);
      }
    }
    __syncthreads();
    // phase 1: logits. wave w handles slots (2w, 2w+1) for rows = lane
    {
      const int s0 = w*2;
      float d0 = 0.f, d1 = 0.f;
      const uint32_t* xr = xs + lane*135;
      #pragma unroll
      for (int dp = 0; dp < 128; ++dp){
        uint32_t x = xr[dp];
        uint2 q = *(const uint2*)(qs + dp*8 + s0);
        d0 = fdot2u(x, q.x, d0);
        d1 = fdot2u(x, q.y, d1);
      }
      *(float2*)(lg + lane*12 + s0) = make_float2(d0, d1);
    }
    __syncthreads();
    // phase 2: softmax over 8 slots (wave 0)
    if (t < 64){
      float l[8];
      float4 a = *(const float4*)(lg + t*12);
      float4 b4 = *(const float4*)(lg + t*12 + 4);
      l[0]=a.x; l[1]=a.y; l[2]=a.z; l[3]=a.w;
      l[4]=b4.x; l[5]=b4.y; l[6]=b4.z; l[7]=b4.w;
      #pragma unroll
      for (int s = 0; s < 8; ++s) l[s] = (l[s] + cs[s]) * 0.0625f;
      float mx = l[0];
      #pragma unroll
      for (int s = 1; s < 8; ++s) mx = fmaxf(mx, l[s]);
      float sum = 0.f;
      #pragma unroll
      for (int s = 0; s < 8; ++s){ l[s] = __expf(l[s] - mx); sum += l[s]; }
      float inv = 1.0f / sum;
      #pragma unroll
      for (int s = 0; s < 8; ++s){ l[s] = l[s]*inv + 1e-8f; asl[s] += l[s]; }
      float4 o0 = make_float4(l[0], l[1], l[2], l[3]);
      float4 o1 = make_float4(l[4], l[5], l[6], l[7]);
      *(float4*)(lg + t*12) = o0;
      *(float4*)(lg + t*12 + 4) = o1;
      if (LAST){
        float4* ap = (float4*)(attn_out + (size_t)(gr0 + t)*8);
        ap[0] = o0; ap[1] = o1;
      }
    }
    __syncthreads();
    // phase 3: column accumulate u[s, d=t] over 64 rows
    {
      const uint32_t* xc = xs + (t >> 1);
      #pragma unroll 8
      for (int r = 0; r < 64; ++r){
        uint32_t u = xc[r*135];
        float x = __half2float(__ushort_as_half((unsigned short)(u >> shf)));
        float4 a0 = *(const float4*)(lg + r*12);
        float4 a1 = *(const float4*)(lg + r*12 + 4);
        up[0] += a0.x*x; up[1] += a0.y*x; up[2] += a0.z*x; up[3] += a0.w*x;
        up[4] += a1.x*x; up[5] += a1.y*x; up[6] += a1.z*x; up[7] += a1.w*x;
      }
    }
  }
  #pragma unroll
  for (int s = 0; s < 8; ++s) atomicAdd(&uacc[(b*8 + s)*256 + t], up[s]);
  if (t < 64){
    #pragma unroll
    for (int s = 0; s < 8; ++s){
      float v = wsum64(asl[s]);
      if (t == 0) atomicAdd(&asum[b*8 + s], v);
    }
  }
}

// ---------------- per-iter: updates = (u/Asum)@wvT + bv ----------------
__global__ __launch_bounds__(256) void k_upd(
  const float* __restrict__ uacc, const float* __restrict__ asum,
  const float* __restrict__ wvT, const float* __restrict__ bv,
  float* __restrict__ updv)
{
  __shared__ float un[256];
  int r = blockIdx.x, t = threadIdx.x;
  float inv = 1.0f / asum[r];
  un[t] = uacc[r*256 + t] * inv;
  __syncthreads();
  float acc = bv[t];
  #pragma unroll 4
  for (int e = 0; e < 256; ++e) acc += un[e] * wvT[e*256 + t];
  updv[r*256 + t] = acc;
}

// ---------------- per-iter: GRU gate pre-activations ----------------
// grid (6,32): cg 0..2 -> gx segment, 3..5 -> gh segment; rg = 8-row group
__global__ __launch_bounds__(256) void k_gxgh(
  const float* __restrict__ upd, const float* __restrict__ slots,
  const float* __restrict__ wihT, const float* __restrict__ whhT,
  const float* __restrict__ bih, const float* __restrict__ bhh,
  float* __restrict__ gx, float* __restrict__ gh)
{
  __shared__ float inT[256*8];
  int cg = blockIdx.x, rg = blockIdx.y, t = threadIdx.x;
  bool isH = cg >= 3;
  int seg = isH ? cg - 3 : cg;
  const float* in = isH ? slots : upd;
  const float* wT = isH ? whhT : wihT;
  const float* bb = isH ? bhh : bih;
  float* outp = isH ? gh : gx;
  for (int i = t; i < 2048; i += 256){
    int r = i >> 8, e = i & 255;
    inT[e*8 + r] = in[(rg*8 + r)*256 + e];
  }
  __syncthreads();
  int col = seg*256 + t;
  float acc[8] = {0,0,0,0,0,0,0,0};
  #pragma unroll 2
  for (int e = 0; e < 256; ++e){
    float wv_ = wT[e*768 + col];
    float4 i0 = *(const float4*)(inT + e*8);
    float4 i1 = *(const float4*)(inT + e*8 + 4);
    acc[0] += i0.x*wv_; acc[1] += i0.y*wv_; acc[2] += i0.z*wv_; acc[3] += i0.w*wv_;
    acc[4] += i1.x*wv_; acc[5] += i1.y*wv_; acc[6] += i1.z*wv_; acc[7] += i1.w*wv_;
  }
  float bias = bb[col];
  #pragma unroll
  for (int r = 0; r < 8; ++r) outp[(rg*8 + r)*768 + col] = acc[r] + bias;
}

// ---------------- per-iter: gate math + LN_m ----------------
__global__ __launch_bounds__(256) void k_gate(
  const float* __restrict__ gx, const float* __restrict__ gh,
  const float* __restrict__ slots, const float* __restrict__ lmg,
  const float* __restrict__ lmb, float* __restrict__ smid,
  float* __restrict__ sln)
{
  __shared__ float red[4];
  int r = blockIdx.x, t = threadIdx.x;
  const float* gxr = gx + r*768;
  const float* ghr = gh + r*768;
  float xr = gxr[t], xz = gxr[256 + t], xn = gxr[512 + t];
  float hr = ghr[t], hz = ghr[256 + t], hn = ghr[512 + t];
  float h = slots[r*256 + t];
  float rg = 1.0f/(1.0f + __expf(-(xr + hr)));
  float zg = 1.0f/(1.0f + __expf(-(xz + hz)));
  float ng = tanhf(xn + rg*hn);
  float sp = (1.0f - zg)*ng + zg*h;
  smid[r*256 + t] = sp;
  float s1 = block_sum256(sp, red);
  float s2 = block_sum256(sp*sp, red);
  float m = s1 * (1.0f/256.0f);
  float var = s2 * (1.0f/256.0f) - m*m;
  float rstd = rsqrtf(var + 1e-5f);
  sln[r*256 + t] = (sp - m)*rstd*lmg[t] + lmb[t];
}

// ---------------- per-iter: h = relu(sln@w1T + b1) ----------------
__global__ __launch_bounds__(256) void k_mlp1(
  const float* __restrict__ sln, const float* __restrict__ w1T,
  const float* __restrict__ b1, float* __restrict__ hbuf)
{
  __shared__ float inT[256*8];
  int cg = blockIdx.x, rg = blockIdx.y, t = threadIdx.x;
  for (int i = t; i < 2048; i += 256){
    int r = i >> 8, e = i & 255;
    inT[e*8 + r] = sln[(rg*8 + r)*256 + e];
  }
  __syncthreads();
  int col = cg*256 + t;
  float acc[8] = {0,0,0,0,0,0,0,0};
  #pragma unroll 2
  for (int e = 0; e < 256; ++e){
    float wv_ = w1T[e*512 + col];
    float4 i0 = *(const float4*)(inT + e*8);
    float4 i1 = *(const float4*)(inT + e*8 + 4);
    acc[0] += i0.x*wv_; acc[1] += i0.y*wv_; acc[2] += i0.z*wv_; acc[3] += i0.w*wv_;
    acc[4] += i1.x*wv_; acc[5] += i1.y*wv_; acc[6] += i1.z*wv_; acc[7] += i1.w*wv_;
  }
  float bias = b1[col];
  #pragma unroll
  for (int r = 0; r < 8; ++r) hbuf[(rg*8 + r)*512 + col] = fmaxf(acc[r] + bias, 0.0f);
}

// ---------------- per-iter: slots = smid + h@w2T + b2 ----------------
__global__ __launch_bounds__(256) void k_mlp2(
  const float* __restrict__ hbuf, const float* __restrict__ w2T,
  const float* __restrict__ b2, const float* __restrict__ smid,
  float* __restrict__ S0)
{
  __shared__ float hT[512*4];
  int rg = blockIdx.x, t = threadIdx.x;   // 64 blocks x 4 rows
  for (int i = t; i < 2048; i += 256){
    int r = i >> 9, e = i & 511;
    hT[e*4 + r] = hbuf[(rg*4 + r)*512 + e];
  }
  __syncthreads();
  float acc[4] = {0,0,0,0};
  #pragma unroll 2
  for (int e = 0; e < 512; ++e){
    float wv_ = w2T[e*256 + t];
    float4 hv = *(const float4*)(hT + e*4);
    acc[0] += hv.x*wv_; acc[1] += hv.y*wv_; acc[2] += hv.z*wv_; acc[3] += hv.w*wv_;
  }
  float bias = b2[t];
  #pragma unroll
  for (int r = 0; r < 4; ++r){
    int row = rg*4 + r;
    S0[row*256 + t] = smid[row*256 + t] + acc[r] + bias;
  }
}

// ---------------- final output: slots copy + attn renormalize ----------------
__global__ __launch_bounds__(256) void k_out(
  const float* __restrict__ S0, const float* __restrict__ asum,
  float* __restrict__ out)
{
  int i = blockIdx.x * 256 + threadIdx.x;
  if (i < 65536) out[i] = S0[i];
  else {
    int j = i - 65536;
    int b = j >> 15;   // 4096*8
    int s = j & 7;
    out[i] = out[i] * (1.0f / asum[b*8 + s]);
  }
}

extern "C" void kernel_launch(void* const* d_in, const int* in_sizes, int n_in,
                              void* d_out, int out_size, void* d_ws, size_t ws_size,
                              hipStream_t stream) {
  const float* inputs = (const float*)d_in[0];
  const float* noise  = (const float*)d_in[1];
  const float* mu     = (const float*)d_in[2];
  const float* sigraw = (const float*)d_in[3];
  const float* lng    = (const float*)d_in[4];
  const float* lnb    = (const float*)d_in[5];
  const float* lsg    = (const float*)d_in[6];
  const float* lsb    = (const float*)d_in[7];
  const float* lmg    = (const float*)d_in[8];
  const float* lmb    = (const float*)d_in[9];
  const float* wq     = (const float*)d_in[10];
  const float* bq     = (const float*)d_in[11];
  const float* wk     = (const float*)d_in[12];
  const float* bk     = (const float*)d_in[13];
  const float* wv     = (const float*)d_in[14];
  const float* bv     = (const float*)d_in[15];
  const float* wih    = (const float*)d_in[16];
  const float* whh    = (const float*)d_in[17];
  const float* bih    = (const float*)d_in[18];
  const float* bhh    = (const float*)d_in[19];
  const float* w1     = (const float*)d_in[20];
  const float* b1     = (const float*)d_in[21];
  const float* w2     = (const float*)d_in[22];
  const float* b2     = (const float*)d_in[23];
  float* out = (float*)d_out;

  const bool xf16 = ws_size >= 74844160ull;
  char* w = (char*)d_ws;
  size_t o = 0;
  uint32_t* XH = (uint32_t*)w;       if (xf16) o += 67108864;
  float* RS  = (float*)(w + o); o += 1048576;
  uint32_t* QT = (uint32_t*)(w + o); o += 131072;
  float* CV  = (float*)(w + o); o += 1024;
  float* UA  = (float*)(w + o); o += 262144;
  float* AS  = (float*)(w + o); o += 1024;
  float* S0  = (float*)(w + o); o += 262144;
  float* SM  = (float*)(w + o); o += 262144;
  float* SL  = (float*)(w + o); o += 262144;
  float* HH  = (float*)(w + o); o += 524288;
  float* GX  = (float*)(w + o); o += 786432;
  float* GH  = (float*)(w + o); o += 786432;
  float* UP  = (float*)(w + o); o += 262144;
  float* WQT = (float*)(w + o); o += 262144;
  float* WVT = (float*)(w + o); o += 262144;
  float* WIHT= (float*)(w + o); o += 786432;
  float* WHHT= (float*)(w + o); o += 786432;
  float* W1T = (float*)(w + o); o += 524288;
  float* W2T = (float*)(w + o); o += 524288;

  k_tr<<<3072, 256, 0, stream>>>(wq, wv, wih, whh, w1, w2, WQT, WVT, WIHT, WHHT, W1T, W2T);
  if (xf16) k_ln<true><<<32768, 256, 0, stream>>>(inputs, lng, lnb, XH, RS);
  else      k_ln<false><<<32768, 256, 0, stream>>>(inputs, lng, lnb, XH, RS);
  k_init<<<256, 256, 0, stream>>>(noise, mu, sigraw, S0);

  for (int it = 0; it < 3; ++it){
    bool last = (it == 2);
    k_qqt<<<256, 256, 0, stream>>>(S0, lsg, lsb, WQT, bq, wk, bk, QT, CV, UA, AS);
    dim3 ga(16, 32);
    if (xf16){
      if (last) k_attn<true,true ><<<ga, 256, 0, stream>>>(XH, inputs, RS, lng, lnb, QT, CV, UA, AS, out + 65536);
      else      k_attn<true,false><<<ga, 256, 0, stream>>>(XH, inputs, RS, lng, lnb, QT, CV, UA, AS, out + 65536);
    } else {
      if (last) k_attn<false,true ><<<ga, 256, 0, stream>>>(XH, inputs, RS, lng, lnb, QT, CV, UA, AS, out + 65536);
      else      k_attn<false,false><<<ga, 256, 0, stream>>>(XH, inputs, RS, lng, lnb, QT, CV, UA, AS, out + 65536);
    }
    k_upd<<<256, 256, 0, stream>>>(UA, AS, WVT, bv, UP);
    k_gxgh<<<dim3(6, 32), 256, 0, stream>>>(UP, S0, WIHT, WHHT, bih, bhh, GX, GH);
    k_gate<<<256, 256, 0, stream>>>(GX, GH, S0, lmg, lmb, SM, SL);
    k_mlp1<<<dim3(2, 32), 256, 0, stream>>>(SL, W1T, b1, HH);
    k_mlp2<<<64, 256, 0, stream>>>(HH, W2T, b2, SM, S0);
  }
  k_out<<<4352, 256, 0, stream>>>(S0, AS, out);
}

// Round 2
// 893.086 us; speedup vs baseline: 1.1073x; 1.1073x over previous
//
#include <hip/hip_runtime.h>
#include <hip/hip_fp16.h>
#include <cstdint>

#define DEV static __device__ __forceinline__

typedef _Float16 f16x2 __attribute__((ext_vector_type(2)));

DEV float fdot2u(uint32_t a, uint32_t b, float c){
  union U { uint32_t u; f16x2 h; };
  U ua; ua.u = a; U ub; ub.u = b;
#if __has_builtin(__builtin_amdgcn_fdot2)
  return __builtin_amdgcn_fdot2(ua.h, ub.h, c, false);
#else
  return c + (float)ua.h[0]*(float)ub.h[0] + (float)ua.h[1]*(float)ub.h[1];
#endif
}

DEV float wsum64(float v){
  #pragma unroll
  for (int o = 32; o; o >>= 1) v += __shfl_xor(v, o);
  return v;
}

DEV uint32_t pack2h(float a, float b){
  __half ha = __float2half(a), hb = __float2half(b);
  return (uint32_t)__half_as_ushort(ha) | ((uint32_t)__half_as_ushort(hb) << 16);
}

// ---------------- weight transposes (once per call) ----------------
__global__ __launch_bounds__(256) void k_tr(
  const float* __restrict__ wq, const float* __restrict__ wv,
  const float* __restrict__ wih, const float* __restrict__ whh,
  const float* __restrict__ w1, const float* __restrict__ w2,
  float* __restrict__ wqT, float* __restrict__ wvT,
  float* __restrict__ wihT, float* __restrict__ whhT,
  float* __restrict__ w1T, float* __restrict__ w2T)
{
  int gid = blockIdx.x * 256 + threadIdx.x;
  if (gid < 65536){ int e = gid >> 8, d = gid & 255; wqT[gid] = wq[d*256 + e]; }
  else if (gid < 131072){ int g2 = gid - 65536; int e = g2 >> 8, d = g2 & 255; wvT[g2] = wv[d*256 + e]; }
  else if (gid < 327680){ int g2 = gid - 131072; int e = g2 / 768, j = g2 - e*768; wihT[g2] = wih[j*256 + e]; }
  else if (gid < 524288){ int g2 = gid - 327680; int e = g2 / 768, j = g2 - e*768; whhT[g2] = whh[j*256 + e]; }
  else if (gid < 655360){ int g2 = gid - 524288; int e = g2 >> 9, j = g2 & 511; w1T[g2] = w1[j*256 + e]; }
  else { int g2 = gid - 655360; int e2 = g2 >> 8, d = g2 & 255; w2T[g2] = w2[d*512 + e2]; }
}

// ---------------- input LayerNorm -> x_hat (f16 pairs) ----------------
__global__ __launch_bounds__(256) void k_ln(
  const float* __restrict__ xin, const float* __restrict__ g,
  const float* __restrict__ b, uint32_t* __restrict__ xhat)
{
  int row = blockIdx.x * 4 + (threadIdx.x >> 6);
  int lane = threadIdx.x & 63;
  const float4 xv = ((const float4*)(xin + (size_t)row * 256))[lane];
  float s1 = wsum64(xv.x + xv.y + xv.z + xv.w);
  float s2 = wsum64(xv.x*xv.x + xv.y*xv.y + xv.z*xv.z + xv.w*xv.w);
  float m = s1 * (1.0f/256.0f);
  float var = s2 * (1.0f/256.0f) - m*m;
  float rstd = rsqrtf(var + 1e-5f);
  float4 gv = ((const float4*)g)[lane];
  float4 bv = ((const float4*)b)[lane];
  float y0 = (xv.x - m)*rstd*gv.x + bv.x;
  float y1 = (xv.y - m)*rstd*gv.y + bv.y;
  float y2 = (xv.z - m)*rstd*gv.z + bv.z;
  float y3 = (xv.w - m)*rstd*gv.w + bv.w;
  ((uint2*)(xhat + (size_t)row * 128))[lane] = make_uint2(pack2h(y0,y1), pack2h(y2,y3));
}

// ---------------- fused slot-update chain ----------------
// MODE 0: init slots from mu/sigma/noise, then q-chain + zero accum
// MODE 1: full chain (upd/GRU/LN/MLP) + q-chain + zero accum
// MODE 2: full chain only (final), leave asum intact for k_out
// grid: 64 blocks x 512 threads; block handles 4 rows (same batch b)
template<int MODE>
__global__ __launch_bounds__(512) void k_slot(
  const float* __restrict__ noise, const float* __restrict__ mu,
  const float* __restrict__ sigraw, float* __restrict__ S0,
  const float* __restrict__ uacc, const float* __restrict__ asum,
  const float* __restrict__ WVT, const float* __restrict__ bv,
  const float* __restrict__ WIHT, const float* __restrict__ WHHT,
  const float* __restrict__ bih, const float* __restrict__ bhh,
  const float* __restrict__ lmg, const float* __restrict__ lmb,
  const float* __restrict__ W1T, const float* __restrict__ b1,
  const float* __restrict__ W2T, const float* __restrict__ b2,
  const float* __restrict__ lsg, const float* __restrict__ lsb,
  const float* __restrict__ WQT, const float* __restrict__ bq,
  const float* __restrict__ wk, const float* __restrict__ bk,
  uint32_t* __restrict__ QTH, float* __restrict__ CV,
  float* __restrict__ uacc_z, float* __restrict__ asum_z)
{
  __shared__ float hs[4][256];
  __shared__ float un[4][256];
  __shared__ float us[4][256];
  __shared__ float gxl[4][768];
  __shared__ float ghl[4][768];
  __shared__ float spb[4][256];
  __shared__ float sln[4][256];
  __shared__ float hb[4][512];
  __shared__ float qtl[4][256];
  __shared__ float redA[8], redB[8], redC[8], redD[8];
  __shared__ float ainv[4];

  const int t = threadIdx.x;
  const int rr = t >> 8;          // 0..1 : this thread covers rows rr and rr+2
  const int c  = t & 255;
  const int w8 = t >> 6;          // wave 0..7
  const int lane = t & 63;
  const int r0 = blockIdx.x * 4;  // global row base (b*8+s)
  const int b  = r0 >> 3;
  const int sbase = (blockIdx.x & 1) * 4;

  if (MODE == 0){
    for (int i = t; i < 1024; i += 512){
      int row = i >> 8, cc = i & 255;
      float x = sigraw[cc];
      float sp = (x > 20.0f) ? x : log1pf(__expf(x));
      float v = mu[cc] + sp * noise[(r0+row)*256 + cc];
      hs[row][cc] = v;
      S0[(r0+row)*256 + cc] = v;
    }
    __syncthreads();
  } else {
    if (t < 4) ainv[t] = 1.0f / asum[r0 + t];
    __syncthreads();
    for (int i = t; i < 1024; i += 512){
      int row = i >> 8, cc = i & 255;
      hs[row][cc] = S0[(r0+row)*256 + cc];
      un[row][cc] = uacc[(r0+row)*256 + cc] * ainv[row];
    }
    __syncthreads();
    // updates = (u/Asum) @ wvT + bv
    {
      float a0 = 0.f, a1 = 0.f;
      #pragma unroll 4
      for (int e = 0; e < 256; ++e){
        float w = WVT[e*256 + c];
        a0 += un[rr][e] * w;
        a1 += un[rr+2][e] * w;
      }
      float bb = bv[c];
      us[rr][c] = a0 + bb;
      us[rr+2][c] = a1 + bb;
    }
    __syncthreads();
    // GRU gate pre-activations: waves 0-3 -> gx (from updates), waves 4-7 -> gh (from slots)
    {
      const float (*IN)[256] = rr ? hs : us;
      const float* WT = rr ? WHHT : WIHT;
      const float* BB = rr ? bhh : bih;
      float (*OUT)[768] = rr ? ghl : gxl;
      for (int g = 0; g < 3; ++g){
        int col = g*256 + c;
        float a0=0.f, a1=0.f, a2=0.f, a3=0.f;
        #pragma unroll 4
        for (int e = 0; e < 256; ++e){
          float w = WT[e*768 + col];
          a0 += IN[0][e]*w; a1 += IN[1][e]*w; a2 += IN[2][e]*w; a3 += IN[3][e]*w;
        }
        float bb = BB[col];
        OUT[0][col]=a0+bb; OUT[1][col]=a1+bb; OUT[2][col]=a2+bb; OUT[3][col]=a3+bb;
      }
    }
    __syncthreads();
    // gate math + LN_m
    {
      float sp0, sp1;
      {
        int row = rr;
        float xr=gxl[row][c], xz=gxl[row][256+c], xn=gxl[row][512+c];
        float hr=ghl[row][c], hz=ghl[row][256+c], hn=ghl[row][512+c];
        float h = hs[row][c];
        float rg = 1.f/(1.f + __expf(-(xr+hr)));
        float zg = 1.f/(1.f + __expf(-(xz+hz)));
        float ng = tanhf(xn + rg*hn);
        sp0 = (1.f - zg)*ng + zg*h;
      }
      {
        int row = rr+2;
        float xr=gxl[row][c], xz=gxl[row][256+c], xn=gxl[row][512+c];
        float hr=ghl[row][c], hz=ghl[row][256+c], hn=ghl[row][512+c];
        float h = hs[row][c];
        float rg = 1.f/(1.f + __expf(-(xr+hr)));
        float zg = 1.f/(1.f + __expf(-(xz+hz)));
        float ng = tanhf(xn + rg*hn);
        sp1 = (1.f - zg)*ng + zg*h;
      }
      spb[rr][c] = sp0; spb[rr+2][c] = sp1;
      float a = wsum64(sp0), bs = wsum64(sp0*sp0);
      float cc2 = wsum64(sp1), dd = wsum64(sp1*sp1);
      if (lane == 0){ redA[w8]=a; redB[w8]=bs; redC[w8]=cc2; redD[w8]=dd; }
      __syncthreads();
      int base = rr*4;
      float s1a = redA[base]+redA[base+1]+redA[base+2]+redA[base+3];
      float s2a = redB[base]+redB[base+1]+redB[base+2]+redB[base+3];
      float s1b = redC[base]+redC[base+1]+redC[base+2]+redC[base+3];
      float s2b = redD[base]+redD[base+1]+redD[base+2]+redD[base+3];
      float m0 = s1a*(1.f/256.f), v0 = s2a*(1.f/256.f) - m0*m0, rs0 = rsqrtf(v0 + 1e-5f);
      float m1 = s1b*(1.f/256.f), v1 = s2b*(1.f/256.f) - m1*m1, rs1 = rsqrtf(v1 + 1e-5f);
      sln[rr][c]   = (sp0 - m0)*rs0*lmg[c] + lmb[c];
      sln[rr+2][c] = (sp1 - m1)*rs1*lmg[c] + lmb[c];
    }
    __syncthreads();
    // h = relu(sln @ w1T + b1)
    {
      float a0=0.f, a1=0.f, a2=0.f, a3=0.f;
      #pragma unroll 4
      for (int e = 0; e < 256; ++e){
        float w = W1T[e*512 + t];
        a0 += sln[0][e]*w; a1 += sln[1][e]*w; a2 += sln[2][e]*w; a3 += sln[3][e]*w;
      }
      float bb = b1[t];
      hb[0][t]=fmaxf(a0+bb,0.f); hb[1][t]=fmaxf(a1+bb,0.f);
      hb[2][t]=fmaxf(a2+bb,0.f); hb[3][t]=fmaxf(a3+bb,0.f);
    }
    __syncthreads();
    // slots = smid + h @ w2T + b2
    {
      float a0=0.f, a1=0.f;
      #pragma unroll 4
      for (int e = 0; e < 512; ++e){
        float w = W2T[e*256 + c];
        a0 += hb[rr][e]*w;
        a1 += hb[rr+2][e]*w;
      }
      float bb = b2[c];
      float sn0 = spb[rr][c]   + a0 + bb;
      float sn1 = spb[rr+2][c] + a1 + bb;
      S0[(r0+rr)*256 + c]   = sn0;
      S0[(r0+rr+2)*256 + c] = sn1;
      hs[rr][c] = sn0; hs[rr+2][c] = sn1;
    }
    __syncthreads();
  }

  if (MODE != 2){
    // LN_s(slots) -> q -> c, qtilde (packed) ; zero accumulators for next attn
    float v0 = hs[rr][c], v1 = hs[rr+2][c];
    float a = wsum64(v0), bs = wsum64(v0*v0);
    float cc2 = wsum64(v1), dd = wsum64(v1*v1);
    if (lane == 0){ redA[w8]=a; redB[w8]=bs; redC[w8]=cc2; redD[w8]=dd; }
    __syncthreads();
    int base = rr*4;
    float s1a = redA[base]+redA[base+1]+redA[base+2]+redA[base+3];
    float s2a = redB[base]+redB[base+1]+redB[base+2]+redB[base+3];
    float s1b = redC[base]+redC[base+1]+redC[base+2]+redC[base+3];
    float s2b = redD[base]+redD[base+1]+redD[base+2]+redD[base+3];
    float m0 = s1a*(1.f/256.f), vv0 = s2a*(1.f/256.f) - m0*m0, rs0 = rsqrtf(vv0 + 1e-5f);
    float m1 = s1b*(1.f/256.f), vv1 = s2b*(1.f/256.f) - m1*m1, rs1 = rsqrtf(vv1 + 1e-5f);
    sln[rr][c]   = (v0 - m0)*rs0*lsg[c] + lsb[c];
    sln[rr+2][c] = (v1 - m1)*rs1*lsg[c] + lsb[c];
    __syncthreads();
    float q0 = 0.f, q1 = 0.f;
    #pragma unroll 4
    for (int e = 0; e < 256; ++e){
      float w = WQT[e*256 + c];
      q0 += sln[rr][e]*w; q1 += sln[rr+2][e]*w;
    }
    float bb = bq[c];
    q0 += bb; q1 += bb;
    float p0 = wsum64(bk[c]*q0), p1 = wsum64(bk[c]*q1);
    if (lane == 0){ redA[w8]=p0; redB[w8]=p1; }
    un[rr][c] = q0; un[rr+2][c] = q1;   // reuse un as q storage
    __syncthreads();
    {
      float cv0 = redA[base]+redA[base+1]+redA[base+2]+redA[base+3];
      float cv1 = redB[base]+redB[base+1]+redB[base+2]+redB[base+3];
      if (c == 0){ CV[r0+rr] = cv0; CV[r0+rr+2] = cv1; }
    }
    float t0 = 0.f, t1 = 0.f;
    #pragma unroll 4
    for (int e = 0; e < 256; ++e){
      float w = wk[e*256 + c];
      t0 += un[rr][e]*w; t1 += un[rr+2][e]*w;
    }
    qtl[rr][c] = t0; qtl[rr+2][c] = t1;
    __syncthreads();
    if (c < 128){
      uint32_t ph0 = pack2h(qtl[rr][2*c],   qtl[rr][2*c+1]);
      uint32_t ph1 = pack2h(qtl[rr+2][2*c], qtl[rr+2][2*c+1]);
      QTH[b*1024 + c*8 + sbase + rr]     = ph0;
      QTH[b*1024 + c*8 + sbase + rr + 2] = ph1;
    }
    for (int i = t; i < 1024; i += 512){
      int row = i >> 8, cc = i & 255;
      uacc_z[(r0+row)*256 + cc] = 0.f;
    }
    if (t < 4) asum_z[r0 + t] = 0.f;
  }
}

// ---------------- fused attention pass ----------------
// grid (16,32): chunk, b. 256 rows/block in 4 subtiles of 64.
template<bool LAST>
__global__ __launch_bounds__(256) void k_attn(
  const uint32_t* __restrict__ xhat,
  const uint32_t* __restrict__ qtpk, const float* __restrict__ cvec,
  float* __restrict__ uacc, float* __restrict__ asum,
  float* __restrict__ attn_out)
{
  __shared__ uint32_t xs[64*135];   // 64 rows x 128 f16-pairs, stride 135 dwords
  __shared__ float lg[64*12];       // logits / attn, stride 12
  __shared__ uint32_t qs[1024];     // q-tilde packed [dp][8]
  __shared__ float cs[8];
  const int b = blockIdx.y, chunk = blockIdx.x;
  const int t = threadIdx.x;
  const int lane = t & 63, w = t >> 6;
  for (int i = t; i < 1024; i += 256) qs[i] = qtpk[b*1024 + i];
  if (t < 8) cs[t] = cvec[b*8 + t];
  float up[8] = {0,0,0,0,0,0,0,0};
  float asl[8] = {0,0,0,0,0,0,0,0};
  const int shf = (t & 1) * 16;
  for (int st = 0; st < 4; ++st){
    const int gr0 = b*4096 + chunk*256 + st*64;
    __syncthreads();
    #pragma unroll
    for (int k = 0; k < 8; ++k){
      int c4 = k*256 + t;
      int row = c4 >> 5, j = c4 & 31;
      uint4 dv = ((const uint4*)xhat)[(size_t)(gr0 + row)*32 + j];
      uint32_t* dst = xs + row*135 + j*4;
      dst[0] = dv.x; dst[1] = dv.y; dst[2] = dv.z; dst[3] = dv.w;
    }
    __syncthreads();
    // phase 1: logits. wave w handles slots (2w, 2w+1) for rows = lane
    {
      const int s0 = w*2;
      float d0 = 0.f, d1 = 0.f;
      const uint32_t* xr = xs + lane*135;
      #pragma unroll
      for (int dp = 0; dp < 128; ++dp){
        uint32_t x = xr[dp];
        uint2 q = *(const uint2*)(qs + dp*8 + s0);
        d0 = fdot2u(x, q.x, d0);
        d1 = fdot2u(x, q.y, d1);
      }
      *(float2*)(lg + lane*12 + s0) = make_float2(d0, d1);
    }
    __syncthreads();
    // phase 2: softmax over 8 slots (wave 0)
    if (t < 64){
      float l[8];
      float4 a = *(const float4*)(lg + t*12);
      float4 b4 = *(const float4*)(lg + t*12 + 4);
      l[0]=a.x; l[1]=a.y; l[2]=a.z; l[3]=a.w;
      l[4]=b4.x; l[5]=b4.y; l[6]=b4.z; l[7]=b4.w;
      #pragma unroll
      for (int s = 0; s < 8; ++s) l[s] = (l[s] + cs[s]) * 0.0625f;
      float mx = l[0];
      #pragma unroll
      for (int s = 1; s < 8; ++s) mx = fmaxf(mx, l[s]);
      float sum = 0.f;
      #pragma unroll
      for (int s = 0; s < 8; ++s){ l[s] = __expf(l[s] - mx); sum += l[s]; }
      float inv = 1.0f / sum;
      #pragma unroll
      for (int s = 0; s < 8; ++s){ l[s] = l[s]*inv + 1e-8f; asl[s] += l[s]; }
      float4 o0 = make_float4(l[0], l[1], l[2], l[3]);
      float4 o1 = make_float4(l[4], l[5], l[6], l[7]);
      *(float4*)(lg + t*12) = o0;
      *(float4*)(lg + t*12 + 4) = o1;
      if (LAST){
        float4* ap = (float4*)(attn_out + (size_t)(gr0 + t)*8);
        ap[0] = o0; ap[1] = o1;
      }
    }
    __syncthreads();
    // phase 3: column accumulate u[s, d=t] over 64 rows
    {
      const uint32_t* xc = xs + (t >> 1);
      #pragma unroll 8
      for (int r = 0; r < 64; ++r){
        uint32_t u = xc[r*135];
        float x = __half2float(__ushort_as_half((unsigned short)(u >> shf)));
        float4 a0 = *(const float4*)(lg + r*12);
        float4 a1 = *(const float4*)(lg + r*12 + 4);
        up[0] += a0.x*x; up[1] += a0.y*x; up[2] += a0.z*x; up[3] += a0.w*x;
        up[4] += a1.x*x; up[5] += a1.y*x; up[6] += a1.z*x; up[7] += a1.w*x;
      }
    }
  }
  #pragma unroll
  for (int s = 0; s < 8; ++s) atomicAdd(&uacc[(b*8 + s)*256 + t], up[s]);
  if (t < 64){
    #pragma unroll
    for (int s = 0; s < 8; ++s){
      float v = wsum64(asl[s]);
      if (t == 0) atomicAdd(&asum[b*8 + s], v);
    }
  }
}

// ---------------- final output: slots copy + attn renormalize ----------------
__global__ __launch_bounds__(256) void k_out(
  const float* __restrict__ S0, const float* __restrict__ asum,
  float* __restrict__ out)
{
  int i = blockIdx.x * 256 + threadIdx.x;
  if (i < 65536) out[i] = S0[i];
  else {
    int j = i - 65536;
    int b = j >> 15;   // 4096*8
    int s = j & 7;
    out[i] = out[i] * (1.0f / asum[b*8 + s]);
  }
}

extern "C" void kernel_launch(void* const* d_in, const int* in_sizes, int n_in,
                              void* d_out, int out_size, void* d_ws, size_t ws_size,
                              hipStream_t stream) {
  const float* inputs = (const float*)d_in[0];
  const float* noise  = (const float*)d_in[1];
  const float* mu     = (const float*)d_in[2];
  const float* sigraw = (const float*)d_in[3];
  const float* lng    = (const float*)d_in[4];
  const float* lnb    = (const float*)d_in[5];
  const float* lsg    = (const float*)d_in[6];
  const float* lsb    = (const float*)d_in[7];
  const float* lmg    = (const float*)d_in[8];
  const float* lmb    = (const float*)d_in[9];
  const float* wq     = (const float*)d_in[10];
  const float* bq     = (const float*)d_in[11];
  const float* wk     = (const float*)d_in[12];
  const float* bk     = (const float*)d_in[13];
  const float* wv     = (const float*)d_in[14];
  const float* bv     = (const float*)d_in[15];
  const float* wih    = (const float*)d_in[16];
  const float* whh    = (const float*)d_in[17];
  const float* bih    = (const float*)d_in[18];
  const float* bhh    = (const float*)d_in[19];
  const float* w1     = (const float*)d_in[20];
  const float* b1     = (const float*)d_in[21];
  const float* w2     = (const float*)d_in[22];
  const float* b2     = (const float*)d_in[23];
  float* out = (float*)d_out;

  char* w = (char*)d_ws;
  size_t o = 0;
  uint32_t* XH = (uint32_t*)w;  o += 67108864;
  uint32_t* QT = (uint32_t*)(w + o); o += 131072;
  float* CV  = (float*)(w + o); o += 1024;
  float* UA  = (float*)(w + o); o += 262144;
  float* AS  = (float*)(w + o); o += 1024;
  float* S0  = (float*)(w + o); o += 262144;
  float* WQT = (float*)(w + o); o += 262144;
  float* WVT = (float*)(w + o); o += 262144;
  float* WIHT= (float*)(w + o); o += 786432;
  float* WHHT= (float*)(w + o); o += 786432;
  float* W1T = (float*)(w + o); o += 524288;
  float* W2T = (float*)(w + o); o += 524288;

  k_tr<<<3072, 256, 0, stream>>>(wq, wv, wih, whh, w1, w2, WQT, WVT, WIHT, WHHT, W1T, W2T);
  k_ln<<<32768, 256, 0, stream>>>(inputs, lng, lnb, XH);
  k_slot<0><<<64, 512, 0, stream>>>(noise, mu, sigraw, S0, UA, AS,
      WVT, bv, WIHT, WHHT, bih, bhh, lmg, lmb, W1T, b1, W2T, b2,
      lsg, lsb, WQT, bq, wk, bk, QT, CV, UA, AS);

  dim3 ga(16, 32);
  for (int it = 0; it < 3; ++it){
    if (it == 2) k_attn<true ><<<ga, 256, 0, stream>>>(XH, QT, CV, UA, AS, out + 65536);
    else         k_attn<false><<<ga, 256, 0, stream>>>(XH, QT, CV, UA, AS, out + 65536);
    if (it < 2)
      k_slot<1><<<64, 512, 0, stream>>>(noise, mu, sigraw, S0, UA, AS,
          WVT, bv, WIHT, WHHT, bih, bhh, lmg, lmb, W1T, b1, W2T, b2,
          lsg, lsb, WQT, bq, wk, bk, QT, CV, UA, AS);
    else
      k_slot<2><<<64, 512, 0, stream>>>(noise, mu, sigraw, S0, UA, AS,
          WVT, bv, WIHT, WHHT, bih, bhh, lmg, lmb, W1T, b1, W2T, b2,
          lsg, lsb, WQT, bq, wk, bk, QT, CV, UA, AS);
  }
  k_out<<<4352, 256, 0, stream>>>(S0, AS, out);
}

// Round 3
// 477.202 us; speedup vs baseline: 2.0722x; 1.8715x over previous
//
#include <hip/hip_runtime.h>
#include <hip/hip_fp16.h>
#include <cstdint>

#define DEV static __device__ __forceinline__

typedef _Float16 f16x2 __attribute__((ext_vector_type(2)));

DEV float fdot2u(uint32_t a, uint32_t b, float c){
  union U { uint32_t u; f16x2 h; };
  U ua; ua.u = a; U ub; ub.u = b;
#if __has_builtin(__builtin_amdgcn_fdot2)
  return __builtin_amdgcn_fdot2(ua.h, ub.h, c, false);
#else
  return c + (float)ua.h[0]*(float)ub.h[0] + (float)ua.h[1]*(float)ub.h[1];
#endif
}

DEV float wsum64(float v){
  #pragma unroll
  for (int o = 32; o; o >>= 1) v += __shfl_xor(v, o);
  return v;
}

DEV uint32_t pack2h(float a, float b){
  __half ha = __float2half(a), hb = __float2half(b);
  return (uint32_t)__half_as_ushort(ha) | ((uint32_t)__half_as_ushort(hb) << 16);
}

// pack (v_even, v_odd) from lane pairs; result valid on even c only
DEV uint32_t packsh(float v){
  float o = __shfl_xor(v, 1);
  return pack2h(v, o);
}

// ---------------- weight repack to f16 pair-major [e2][N] (once per call) ----------------
// W[N][K] row-major -> Wp[e2][n] = pack(W[n][2e2], W[n][2e2+1])
__global__ __launch_bounds__(256) void k_tr(
  const float* __restrict__ wq, const float* __restrict__ wv,
  const float* __restrict__ wih, const float* __restrict__ whh,
  const float* __restrict__ w1, const float* __restrict__ w2,
  const float* __restrict__ wk,
  uint32_t* __restrict__ WQp, uint32_t* __restrict__ WVp,
  uint32_t* __restrict__ WIHp, uint32_t* __restrict__ WHHp,
  uint32_t* __restrict__ W1p, uint32_t* __restrict__ W2p,
  uint32_t* __restrict__ WKp)
{
  int r = blockIdx.x * 256 + threadIdx.x;
  if (r < 32768){            // wv: N=256,K=256
    int n = r >> 7, e2 = r & 127;
    WVp[e2*256 + n] = pack2h(wv[n*256 + 2*e2], wv[n*256 + 2*e2 + 1]);
  } else if (r < 131072){    // wih: N=768,K=256
    int r2 = r - 32768; int n = r2 >> 7, e2 = r2 & 127;
    WIHp[e2*768 + n] = pack2h(wih[n*256 + 2*e2], wih[n*256 + 2*e2 + 1]);
  } else if (r < 229376){    // whh
    int r2 = r - 131072; int n = r2 >> 7, e2 = r2 & 127;
    WHHp[e2*768 + n] = pack2h(whh[n*256 + 2*e2], whh[n*256 + 2*e2 + 1]);
  } else if (r < 294912){    // w1: N=512,K=256
    int r2 = r - 229376; int n = r2 >> 7, e2 = r2 & 127;
    W1p[e2*512 + n] = pack2h(w1[n*256 + 2*e2], w1[n*256 + 2*e2 + 1]);
  } else if (r < 360448){    // w2: N=256,K=512
    int r2 = r - 294912; int n = r2 >> 8, e2 = r2 & 255;
    W2p[e2*256 + n] = pack2h(w2[n*512 + 2*e2], w2[n*512 + 2*e2 + 1]);
  } else if (r < 393216){    // wq: N=256,K=256
    int r2 = r - 360448; int n = r2 >> 7, e2 = r2 & 127;
    WQp[e2*256 + n] = pack2h(wq[n*256 + 2*e2], wq[n*256 + 2*e2 + 1]);
  } else if (r < 425984){    // wk used as qt[c]=sum_d q[d]*wk[d][c]; already [d][c]
    int r2 = r - 393216; int c = r2 & 255, d2 = r2 >> 8;
    WKp[d2*256 + c] = pack2h(wk[(2*d2)*256 + c], wk[(2*d2+1)*256 + c]);
  }
}

// ---------------- input LayerNorm -> x_hat (f16 pairs) ----------------
__global__ __launch_bounds__(256) void k_ln(
  const float* __restrict__ xin, const float* __restrict__ g,
  const float* __restrict__ b, uint32_t* __restrict__ xhat)
{
  int row = blockIdx.x * 4 + (threadIdx.x >> 6);
  int lane = threadIdx.x & 63;
  const float4 xv = ((const float4*)(xin + (size_t)row * 256))[lane];
  float s1 = wsum64(xv.x + xv.y + xv.z + xv.w);
  float s2 = wsum64(xv.x*xv.x + xv.y*xv.y + xv.z*xv.z + xv.w*xv.w);
  float m = s1 * (1.0f/256.0f);
  float var = s2 * (1.0f/256.0f) - m*m;
  float rstd = rsqrtf(var + 1e-5f);
  float4 gv = ((const float4*)g)[lane];
  float4 bv = ((const float4*)b)[lane];
  float y0 = (xv.x - m)*rstd*gv.x + bv.x;
  float y1 = (xv.y - m)*rstd*gv.y + bv.y;
  float y2 = (xv.z - m)*rstd*gv.z + bv.z;
  float y3 = (xv.w - m)*rstd*gv.w + bv.w;
  ((uint2*)(xhat + (size_t)row * 128))[lane] = make_uint2(pack2h(y0,y1), pack2h(y2,y3));
}

// ---------------- fused slot-update chain ----------------
// 128 blocks x 512 threads; block = 2 rows (same batch). rr2 = t>>8 is the
// "second dimension": row-split for elementwise phases, K-split or matrix-split
// for GEMV phases. All GEMV weights pre-packed f16 pair-major, fed by v_dot2.
template<int MODE>   // 0: init+q-chain, 1: chain+q-chain, 2: chain only
__global__ __launch_bounds__(512) void k_slot(
  const float* __restrict__ noise, const float* __restrict__ mu,
  const float* __restrict__ sigraw, float* __restrict__ S0,
  const float* __restrict__ uacc, const float* __restrict__ asum,
  const uint32_t* __restrict__ WVp, const float* __restrict__ bv,
  const uint32_t* __restrict__ WIHp, const uint32_t* __restrict__ WHHp,
  const float* __restrict__ bih, const float* __restrict__ bhh,
  const float* __restrict__ lmg, const float* __restrict__ lmb,
  const uint32_t* __restrict__ W1p, const float* __restrict__ b1,
  const uint32_t* __restrict__ W2p, const float* __restrict__ b2,
  const float* __restrict__ lsg, const float* __restrict__ lsb,
  const uint32_t* __restrict__ WQp, const float* __restrict__ bq,
  const uint32_t* __restrict__ WKp, const float* __restrict__ bk,
  uint32_t* __restrict__ QTH, float* __restrict__ CV,
  float* __restrict__ uacc_z, float* __restrict__ asum_z)
{
  __shared__ float gx[2][768], gh[2][768];
  __shared__ float spb[2][256];
  __shared__ float part[2][2][256];
  __shared__ uint32_t un2[2][128], hs2[2][128], us2[2][128];
  __shared__ uint32_t sln2[2][128], slnS2[2][128], q2[2][128];
  __shared__ uint32_t hb2[2][256];
  __shared__ float redA[8], redB[8];
  __shared__ float ainv[2];

  const int t = threadIdx.x;
  const int rr2 = t >> 8;         // 0/1
  const int c = t & 255;
  const int lane = t & 63;
  const int w8 = t >> 6;          // wave 0..7
  const int r0 = blockIdx.x * 2;  // global row base (b*8+s)
  const int b = r0 >> 3;
  const int base4 = rr2 * 4;

  float snv;   // new slot value for (row rr2, col c)

  if (MODE == 0){
    float x = sigraw[c];
    float sp = (x > 20.0f) ? x : log1pf(__expf(x));
    snv = mu[c] + sp * noise[(r0+rr2)*256 + c];
    S0[(r0+rr2)*256 + c] = snv;
  } else {
    if (t < 2) ainv[t] = 1.0f / asum[r0 + t];
    __syncthreads();
    float hv = S0[(r0+rr2)*256 + c];
    float unv = uacc[(r0+rr2)*256 + c] * ainv[rr2];
    uint32_t ph = packsh(hv), pu = packsh(unv);
    if (!(c & 1)){ hs2[rr2][c>>1] = ph; un2[rr2][c>>1] = pu; }
    __syncthreads();

    // ---- updates = (u/Asum) @ wv^T + bv : K-split by rr2 ----
    {
      float a0 = 0.f, a1 = 0.f;
      int e0 = rr2 * 64;
      #pragma unroll 8
      for (int e2 = e0; e2 < e0 + 64; ++e2){
        uint32_t w = WVp[e2*256 + c];
        a0 = fdot2u(un2[0][e2], w, a0);
        a1 = fdot2u(un2[1][e2], w, a1);
      }
      part[rr2][0][c] = a0; part[rr2][1][c] = a1;
    }
    __syncthreads();
    {
      float usv = part[0][rr2][c] + part[1][rr2][c] + bv[c];
      uint32_t p = packsh(usv);
      if (!(c & 1)) us2[rr2][c>>1] = p;
    }
    __syncthreads();

    // ---- GRU gates: rr2=0 -> gx (input us2, W_ih), rr2=1 -> gh (input hs2, W_hh) ----
    {
      const uint32_t* WT = rr2 ? WHHp : WIHp;
      const uint32_t (*IN2)[128] = rr2 ? hs2 : us2;
      float a00=0,a01=0,a10=0,a11=0,a20=0,a21=0;
      #pragma unroll 8
      for (int e2 = 0; e2 < 128; ++e2){
        uint32_t x0 = IN2[0][e2], x1 = IN2[1][e2];
        uint32_t w0 = WT[e2*768 + c];
        uint32_t w1_ = WT[e2*768 + 256 + c];
        uint32_t w2_ = WT[e2*768 + 512 + c];
        a00 = fdot2u(x0, w0, a00);  a01 = fdot2u(x1, w0, a01);
        a10 = fdot2u(x0, w1_, a10); a11 = fdot2u(x1, w1_, a11);
        a20 = fdot2u(x0, w2_, a20); a21 = fdot2u(x1, w2_, a21);
      }
      float (*OUT)[768] = rr2 ? gh : gx;
      OUT[0][c] = a00;     OUT[1][c] = a01;
      OUT[0][256+c] = a10; OUT[1][256+c] = a11;
      OUT[0][512+c] = a20; OUT[1][512+c] = a21;
    }
    __syncthreads();

    // ---- gate math + LN_m ----
    float spv;
    {
      float xr = gx[rr2][c]     + bih[c];
      float xz = gx[rr2][256+c] + bih[256+c];
      float xn = gx[rr2][512+c] + bih[512+c];
      float hr = gh[rr2][c]     + bhh[c];
      float hz = gh[rr2][256+c] + bhh[256+c];
      float hn = gh[rr2][512+c] + bhh[512+c];
      float rg = 1.f/(1.f + __expf(-(xr + hr)));
      float zg = 1.f/(1.f + __expf(-(xz + hz)));
      float ng = tanhf(xn + rg*hn);
      spv = (1.f - zg)*ng + zg*hv;
      spb[rr2][c] = spv;
      float a = wsum64(spv), bs = wsum64(spv*spv);
      if (lane == 0){ redA[w8] = a; redB[w8] = bs; }
    }
    __syncthreads();
    {
      float s1 = redA[base4]+redA[base4+1]+redA[base4+2]+redA[base4+3];
      float s2 = redB[base4]+redB[base4+1]+redB[base4+2]+redB[base4+3];
      float m = s1*(1.f/256.f), var = s2*(1.f/256.f) - m*m;
      float rstd = rsqrtf(var + 1e-5f);
      float slv = (spv - m)*rstd*lmg[c] + lmb[c];
      uint32_t p = packsh(slv);
      if (!(c & 1)) sln2[rr2][c>>1] = p;
    }
    __syncthreads();

    // ---- h = relu(sln @ w1^T + b1): col = t (0..511), 2 row-accs ----
    {
      float a0 = 0.f, a1 = 0.f;
      #pragma unroll 8
      for (int e2 = 0; e2 < 128; ++e2){
        uint32_t w = W1p[e2*512 + t];
        a0 = fdot2u(sln2[0][e2], w, a0);
        a1 = fdot2u(sln2[1][e2], w, a1);
      }
      float bb = b1[t];
      float h0 = fmaxf(a0 + bb, 0.f), h1 = fmaxf(a1 + bb, 0.f);
      float o0 = __shfl_xor(h0, 1), o1 = __shfl_xor(h1, 1);
      if (!(t & 1)){
        hb2[0][t>>1] = pack2h(h0, o0);
        hb2[1][t>>1] = pack2h(h1, o1);
      }
    }
    __syncthreads();

    // ---- slots = smid + h @ w2^T + b2 : K=512, K-split by rr2 ----
    {
      float a0 = 0.f, a1 = 0.f;
      int e0 = rr2 * 128;
      #pragma unroll 8
      for (int e2 = e0; e2 < e0 + 128; ++e2){
        uint32_t w = W2p[e2*256 + c];
        a0 = fdot2u(hb2[0][e2], w, a0);
        a1 = fdot2u(hb2[1][e2], w, a1);
      }
      part[rr2][0][c] = a0; part[rr2][1][c] = a1;
    }
    __syncthreads();
    snv = spb[rr2][c] + part[0][rr2][c] + part[1][rr2][c] + b2[c];
    S0[(r0+rr2)*256 + c] = snv;
  }

  if (MODE != 2){
    // ---- LN_s(new slots) ----
    {
      float a = wsum64(snv), bs = wsum64(snv*snv);
      if (lane == 0){ redA[w8] = a; redB[w8] = bs; }
    }
    __syncthreads();
    {
      float s1 = redA[base4]+redA[base4+1]+redA[base4+2]+redA[base4+3];
      float s2 = redB[base4]+redB[base4+1]+redB[base4+2]+redB[base4+3];
      float m = s1*(1.f/256.f), var = s2*(1.f/256.f) - m*m;
      float rstd = rsqrtf(var + 1e-5f);
      float slv = (snv - m)*rstd*lsg[c] + lsb[c];
      uint32_t p = packsh(slv);
      if (!(c & 1)) slnS2[rr2][c>>1] = p;
    }
    __syncthreads();

    // ---- q = slnS @ wq^T + bq : K-split ----
    {
      float a0 = 0.f, a1 = 0.f;
      int e0 = rr2 * 64;
      #pragma unroll 8
      for (int e2 = e0; e2 < e0 + 64; ++e2){
        uint32_t w = WQp[e2*256 + c];
        a0 = fdot2u(slnS2[0][e2], w, a0);
        a1 = fdot2u(slnS2[1][e2], w, a1);
      }
      part[rr2][0][c] = a0; part[rr2][1][c] = a1;
    }
    __syncthreads();
    float qv_;
    {
      qv_ = part[0][rr2][c] + part[1][rr2][c] + bq[c];
      float p = wsum64(bk[c] * qv_);
      if (lane == 0) redA[w8] = p;
      uint32_t pk = packsh(qv_);
      if (!(c & 1)) q2[rr2][c>>1] = pk;
    }
    __syncthreads();
    {
      float cv = redA[base4]+redA[base4+1]+redA[base4+2]+redA[base4+3];
      if (c == 0) CV[r0 + rr2] = cv;
    }

    // ---- qt = q @ wk (already col-major) : K-split ----
    {
      float a0 = 0.f, a1 = 0.f;
      int e0 = rr2 * 64;
      #pragma unroll 8
      for (int e2 = e0; e2 < e0 + 64; ++e2){
        uint32_t w = WKp[e2*256 + c];
        a0 = fdot2u(q2[0][e2], w, a0);
        a1 = fdot2u(q2[1][e2], w, a1);
      }
      part[rr2][0][c] = a0; part[rr2][1][c] = a1;
    }
    __syncthreads();
    {
      float qtv = part[0][rr2][c] + part[1][rr2][c];
      uint32_t p = packsh(qtv);
      if (!(c & 1)) QTH[b*1024 + (c>>1)*8 + (r0 & 7) + rr2] = p;
    }

    // zero accumulators for next attention pass
    uacc_z[(r0+rr2)*256 + c] = 0.f;
    if (t < 2) asum_z[r0 + t] = 0.f;
  }
}

// ---------------- fused attention pass ----------------
// grid (16,32): chunk, b. 256 rows/block in 4 subtiles of 64.
template<bool LAST>
__global__ __launch_bounds__(256) void k_attn(
  const uint32_t* __restrict__ xhat,
  const uint32_t* __restrict__ qtpk, const float* __restrict__ cvec,
  float* __restrict__ uacc, float* __restrict__ asum,
  float* __restrict__ attn_out)
{
  __shared__ uint32_t xs[64*135];
  __shared__ float lg[64*12];
  __shared__ uint32_t qs[1024];
  __shared__ float cs[8];
  const int b = blockIdx.y, chunk = blockIdx.x;
  const int t = threadIdx.x;
  const int lane = t & 63, w = t >> 6;
  for (int i = t; i < 1024; i += 256) qs[i] = qtpk[b*1024 + i];
  if (t < 8) cs[t] = cvec[b*8 + t];
  float up[8] = {0,0,0,0,0,0,0,0};
  float asl[8] = {0,0,0,0,0,0,0,0};
  const int shf = (t & 1) * 16;
  for (int st = 0; st < 4; ++st){
    const int gr0 = b*4096 + chunk*256 + st*64;
    __syncthreads();
    #pragma unroll
    for (int k = 0; k < 8; ++k){
      int c4 = k*256 + t;
      int row = c4 >> 5, j = c4 & 31;
      uint4 dv = ((const uint4*)xhat)[(size_t)(gr0 + row)*32 + j];
      uint32_t* dst = xs + row*135 + j*4;
      dst[0] = dv.x; dst[1] = dv.y; dst[2] = dv.z; dst[3] = dv.w;
    }
    __syncthreads();
    {
      const int s0 = w*2;
      float d0 = 0.f, d1 = 0.f;
      const uint32_t* xr = xs + lane*135;
      #pragma unroll
      for (int dp = 0; dp < 128; ++dp){
        uint32_t x = xr[dp];
        uint2 q = *(const uint2*)(qs + dp*8 + s0);
        d0 = fdot2u(x, q.x, d0);
        d1 = fdot2u(x, q.y, d1);
      }
      *(float2*)(lg + lane*12 + s0) = make_float2(d0, d1);
    }
    __syncthreads();
    if (t < 64){
      float l[8];
      float4 a = *(const float4*)(lg + t*12);
      float4 b4 = *(const float4*)(lg + t*12 + 4);
      l[0]=a.x; l[1]=a.y; l[2]=a.z; l[3]=a.w;
      l[4]=b4.x; l[5]=b4.y; l[6]=b4.z; l[7]=b4.w;
      #pragma unroll
      for (int s = 0; s < 8; ++s) l[s] = (l[s] + cs[s]) * 0.0625f;
      float mx = l[0];
      #pragma unroll
      for (int s = 1; s < 8; ++s) mx = fmaxf(mx, l[s]);
      float sum = 0.f;
      #pragma unroll
      for (int s = 0; s < 8; ++s){ l[s] = __expf(l[s] - mx); sum += l[s]; }
      float inv = 1.0f / sum;
      #pragma unroll
      for (int s = 0; s < 8; ++s){ l[s] = l[s]*inv + 1e-8f; asl[s] += l[s]; }
      float4 o0 = make_float4(l[0], l[1], l[2], l[3]);
      float4 o1 = make_float4(l[4], l[5], l[6], l[7]);
      *(float4*)(lg + t*12) = o0;
      *(float4*)(lg + t*12 + 4) = o1;
      if (LAST){
        float4* ap = (float4*)(attn_out + (size_t)(gr0 + t)*8);
        ap[0] = o0; ap[1] = o1;
      }
    }
    __syncthreads();
    {
      const uint32_t* xc = xs + (t >> 1);
      #pragma unroll 8
      for (int r = 0; r < 64; ++r){
        uint32_t u = xc[r*135];
        float x = __half2float(__ushort_as_half((unsigned short)(u >> shf)));
        float4 a0 = *(const float4*)(lg + r*12);
        float4 a1 = *(const float4*)(lg + r*12 + 4);
        up[0] += a0.x*x; up[1] += a0.y*x; up[2] += a0.z*x; up[3] += a0.w*x;
        up[4] += a1.x*x; up[5] += a1.y*x; up[6] += a1.z*x; up[7] += a1.w*x;
      }
    }
  }
  #pragma unroll
  for (int s = 0; s < 8; ++s) atomicAdd(&uacc[(b*8 + s)*256 + t], up[s]);
  if (t < 64){
    #pragma unroll
    for (int s = 0; s < 8; ++s){
      float v = wsum64(asl[s]);
      if (t == 0) atomicAdd(&asum[b*8 + s], v);
    }
  }
}

// ---------------- final output: slots copy + attn renormalize ----------------
__global__ __launch_bounds__(256) void k_out(
  const float* __restrict__ S0, const float* __restrict__ asum,
  float* __restrict__ out)
{
  int i = blockIdx.x * 256 + threadIdx.x;
  if (i < 65536) out[i] = S0[i];
  else {
    int j = i - 65536;
    int b = j >> 15;
    int s = j & 7;
    out[i] = out[i] * (1.0f / asum[b*8 + s]);
  }
}

extern "C" void kernel_launch(void* const* d_in, const int* in_sizes, int n_in,
                              void* d_out, int out_size, void* d_ws, size_t ws_size,
                              hipStream_t stream) {
  const float* inputs = (const float*)d_in[0];
  const float* noise  = (const float*)d_in[1];
  const float* mu     = (const float*)d_in[2];
  const float* sigraw = (const float*)d_in[3];
  const float* lng    = (const float*)d_in[4];
  const float* lnb    = (const float*)d_in[5];
  const float* lsg    = (const float*)d_in[6];
  const float* lsb    = (const float*)d_in[7];
  const float* lmg    = (const float*)d_in[8];
  const float* lmb    = (const float*)d_in[9];
  const float* wq     = (const float*)d_in[10];
  const float* bq     = (const float*)d_in[11];
  const float* wk     = (const float*)d_in[12];
  const float* bk     = (const float*)d_in[13];
  const float* wv     = (const float*)d_in[14];
  const float* bv     = (const float*)d_in[15];
  const float* wih    = (const float*)d_in[16];
  const float* whh    = (const float*)d_in[17];
  const float* bih    = (const float*)d_in[18];
  const float* bhh    = (const float*)d_in[19];
  const float* w1     = (const float*)d_in[20];
  const float* b1     = (const float*)d_in[21];
  const float* w2     = (const float*)d_in[22];
  const float* b2     = (const float*)d_in[23];
  float* out = (float*)d_out;

  char* w = (char*)d_ws;
  size_t o = 0;
  uint32_t* XH = (uint32_t*)w;  o += 67108864;
  uint32_t* QT = (uint32_t*)(w + o); o += 131072;
  float* CV  = (float*)(w + o); o += 1024;
  float* UA  = (float*)(w + o); o += 262144;
  float* AS  = (float*)(w + o); o += 1024;
  float* S0  = (float*)(w + o); o += 262144;
  uint32_t* WQp = (uint32_t*)(w + o); o += 131072;
  uint32_t* WVp = (uint32_t*)(w + o); o += 131072;
  uint32_t* WIHp= (uint32_t*)(w + o); o += 393216;
  uint32_t* WHHp= (uint32_t*)(w + o); o += 393216;
  uint32_t* W1p = (uint32_t*)(w + o); o += 262144;
  uint32_t* W2p = (uint32_t*)(w + o); o += 262144;
  uint32_t* WKp = (uint32_t*)(w + o); o += 131072;

  k_tr<<<1664, 256, 0, stream>>>(wq, wv, wih, whh, w1, w2, wk,
                                 WQp, WVp, WIHp, WHHp, W1p, W2p, WKp);
  k_ln<<<32768, 256, 0, stream>>>(inputs, lng, lnb, XH);
  k_slot<0><<<128, 512, 0, stream>>>(noise, mu, sigraw, S0, UA, AS,
      WVp, bv, WIHp, WHHp, bih, bhh, lmg, lmb, W1p, b1, W2p, b2,
      lsg, lsb, WQp, bq, WKp, bk, QT, CV, UA, AS);

  dim3 ga(16, 32);
  for (int it = 0; it < 3; ++it){
    if (it == 2) k_attn<true ><<<ga, 256, 0, stream>>>(XH, QT, CV, UA, AS, out + 65536);
    else         k_attn<false><<<ga, 256, 0, stream>>>(XH, QT, CV, UA, AS, out + 65536);
    if (it < 2)
      k_slot<1><<<128, 512, 0, stream>>>(noise, mu, sigraw, S0, UA, AS,
          WVp, bv, WIHp, WHHp, bih, bhh, lmg, lmb, W1p, b1, W2p, b2,
          lsg, lsb, WQp, bq, WKp, bk, QT, CV, UA, AS);
    else
      k_slot<2><<<128, 512, 0, stream>>>(noise, mu, sigraw, S0, UA, AS,
          WVp, bv, WIHp, WHHp, bih, bhh, lmg, lmb, W1p, b1, W2p, b2,
          lsg, lsb, WQp, bq, WKp, bk, QT, CV, UA, AS);
  }
  k_out<<<4352, 256, 0, stream>>>(S0, AS, out);
}

// Round 4
// 433.591 us; speedup vs baseline: 2.2807x; 1.1006x over previous
//
#include <hip/hip_runtime.h>
#include <hip/hip_fp16.h>
#include <cstdint>

#define DEV static __device__ __forceinline__

typedef _Float16 f16x2 __attribute__((ext_vector_type(2)));

DEV float fdot2u(uint32_t a, uint32_t b, float c){
  union U { uint32_t u; f16x2 h; };
  U ua; ua.u = a; U ub; ub.u = b;
#if __has_builtin(__builtin_amdgcn_fdot2)
  return __builtin_amdgcn_fdot2(ua.h, ub.h, c, false);
#else
  return c + (float)ua.h[0]*(float)ub.h[0] + (float)ua.h[1]*(float)ub.h[1];
#endif
}

DEV float dot4(uint4 x, uint4 w, float a){
  a = fdot2u(x.x, w.x, a); a = fdot2u(x.y, w.y, a);
  a = fdot2u(x.z, w.z, a); a = fdot2u(x.w, w.w, a);
  return a;
}

DEV float wsum64(float v){
  #pragma unroll
  for (int o = 32; o; o >>= 1) v += __shfl_xor(v, o);
  return v;
}

DEV uint32_t pack2h(float a, float b){
  __half ha = __float2half(a), hb = __float2half(b);
  return (uint32_t)__half_as_ushort(ha) | ((uint32_t)__half_as_ushort(hb) << 16);
}

// pack (v_even, v_odd) from lane pairs; result valid on even lane only
DEV uint32_t packsh(float v){
  float o = __shfl_xor(v, 1);
  return pack2h(v, o);
}

DEV uint4 packrow8(const float* p){
  uint4 r;
  r.x = pack2h(p[0], p[1]); r.y = pack2h(p[2], p[3]);
  r.z = pack2h(p[4], p[5]); r.w = pack2h(p[6], p[7]);
  return r;
}

// ---------------- weight repack to f16 uint4 tiles Wp4[e4][col] ----------------
// W[N][K] row-major; e4 covers K-elements [8*e4, 8*e4+8)
__global__ __launch_bounds__(256) void k_tr(
  const float* __restrict__ wq, const float* __restrict__ wv,
  const float* __restrict__ wih, const float* __restrict__ whh,
  const float* __restrict__ w1, const float* __restrict__ w2,
  const float* __restrict__ wk,
  uint4* __restrict__ WQp4, uint4* __restrict__ WVp4,
  uint4* __restrict__ WIHp4, uint4* __restrict__ WHHp4,
  uint4* __restrict__ W1p4, uint4* __restrict__ W2p4,
  uint4* __restrict__ WKp4)
{
  int u = blockIdx.x * 256 + threadIdx.x;
  if (u < 8192){                                  // wv: N=256 K=256
    int e4 = u >> 8, n = u & 255;
    WVp4[u] = packrow8(wv + n*256 + 8*e4);
  } else if (u < 32768){                          // wih: N=768 K=256
    int v = u - 8192; int e4 = v / 768, n = v - e4*768;
    WIHp4[v] = packrow8(wih + n*256 + 8*e4);
  } else if (u < 57344){                          // whh
    int v = u - 32768; int e4 = v / 768, n = v - e4*768;
    WHHp4[v] = packrow8(whh + n*256 + 8*e4);
  } else if (u < 73728){                          // w1: N=512 K=256
    int v = u - 57344; int e4 = v >> 9, n = v & 511;
    W1p4[v] = packrow8(w1 + n*256 + 8*e4);
  } else if (u < 90112){                          // w2: N=256 K=512
    int v = u - 73728; int e4 = v >> 8, n = v & 255;
    W2p4[v] = packrow8(w2 + n*512 + 8*e4);
  } else if (u < 98304){                          // wq: N=256 K=256
    int v = u - 90112; int e4 = v >> 8, n = v & 255;
    WQp4[v] = packrow8(wq + n*256 + 8*e4);
  } else if (u < 106496){                         // wk strided: WKp4[d4][c]
    int v = u - 98304; int d4 = v >> 8, c = v & 255;
    uint4 r;
    r.x = pack2h(wk[(8*d4+0)*256 + c], wk[(8*d4+1)*256 + c]);
    r.y = pack2h(wk[(8*d4+2)*256 + c], wk[(8*d4+3)*256 + c]);
    r.z = pack2h(wk[(8*d4+4)*256 + c], wk[(8*d4+5)*256 + c]);
    r.w = pack2h(wk[(8*d4+6)*256 + c], wk[(8*d4+7)*256 + c]);
    WKp4[v] = r;
  }
}

// ---------------- input LayerNorm -> x_hat (f16 pairs) ----------------
__global__ __launch_bounds__(256) void k_ln(
  const float* __restrict__ xin, const float* __restrict__ g,
  const float* __restrict__ b, uint32_t* __restrict__ xhat)
{
  int row = blockIdx.x * 4 + (threadIdx.x >> 6);
  int lane = threadIdx.x & 63;
  const float4 xv = ((const float4*)(xin + (size_t)row * 256))[lane];
  float s1 = wsum64(xv.x + xv.y + xv.z + xv.w);
  float s2 = wsum64(xv.x*xv.x + xv.y*xv.y + xv.z*xv.z + xv.w*xv.w);
  float m = s1 * (1.0f/256.0f);
  float var = s2 * (1.0f/256.0f) - m*m;
  float rstd = rsqrtf(var + 1e-5f);
  float4 gv = ((const float4*)g)[lane];
  float4 bv = ((const float4*)b)[lane];
  float y0 = (xv.x - m)*rstd*gv.x + bv.x;
  float y1 = (xv.y - m)*rstd*gv.y + bv.y;
  float y2 = (xv.z - m)*rstd*gv.z + bv.z;
  float y3 = (xv.w - m)*rstd*gv.w + bv.w;
  ((uint2*)(xhat + (size_t)row * 128))[lane] = make_uint2(pack2h(y0,y1), pack2h(y2,y3));
}

// ---------------- fused slot-update chain ----------------
// 256 blocks x 512 threads; 1 row (b*8+s) per block.
// h = t>>8 is K-split half (or matrix selector for GRU); c = t&255.
// All weights pre-tiled uint4 f16; inputs in LDS read as uint4 (b128).
template<int MODE>   // 0: init+q-chain, 1: chain+q-chain, 2: chain only
__global__ __launch_bounds__(512) void k_slot(
  const float* __restrict__ noise, const float* __restrict__ mu,
  const float* __restrict__ sigraw, float* __restrict__ S0,
  const float* __restrict__ uacc, const float* __restrict__ asum,
  const uint4* __restrict__ WVp4, const float* __restrict__ bv,
  const uint4* __restrict__ WIHp4, const uint4* __restrict__ WHHp4,
  const float* __restrict__ bih, const float* __restrict__ bhh,
  const float* __restrict__ lmg, const float* __restrict__ lmb,
  const uint4* __restrict__ W1p4, const float* __restrict__ b1,
  const uint4* __restrict__ W2p4, const float* __restrict__ b2,
  const float* __restrict__ lsg, const float* __restrict__ lsb,
  const uint4* __restrict__ WQp4, const float* __restrict__ bq,
  const uint4* __restrict__ WKp4, const float* __restrict__ bk,
  uint32_t* __restrict__ QTH, float* __restrict__ CV,
  float* __restrict__ uacc_z, float* __restrict__ asum_z)
{
  __shared__ float gx[768], gh[768];
  __shared__ float part[512];
  __shared__ uint4 hs4[32], un4[32], us4[32], sln4[32], q4[32];
  __shared__ uint4 hb4[64];
  __shared__ float redA[8], redB[8];

  const int t = threadIdx.x;
  const int h = t >> 8;           // 0/1
  const int c = t & 255;
  const int lane = t & 63;
  const int w8 = t >> 6;          // wave 0..7
  const int r = blockIdx.x;       // global row (b*8+s)
  const int b = r >> 3, s = r & 7;

  float snv = 0.f, spv = 0.f;

  if (MODE == 0){
    if (t < 256){
      float x = sigraw[c];
      float sp = (x > 20.0f) ? x : log1pf(__expf(x));
      snv = mu[c] + sp * noise[r*256 + c];
      S0[r*256 + c] = snv;
    }
  } else {
    float ainv = 1.0f / asum[r];
    float hv = 0.f;
    if (t < 256){
      hv = S0[r*256 + c];
      float unv = uacc[r*256 + c] * ainv;
      uint32_t ph = packsh(hv), pu = packsh(unv);
      if (!(c & 1)){
        ((uint32_t*)hs4)[c>>1] = ph;
        ((uint32_t*)un4)[c>>1] = pu;
      }
    }
    __syncthreads();

    // ---- updates = (u/Asum) @ wv^T + bv : K-split by h ----
    {
      float a = 0.f;
      #pragma unroll 8
      for (int e4 = h*16; e4 < h*16 + 16; ++e4)
        a = dot4(un4[e4], WVp4[e4*256 + c], a);
      part[t] = a;
    }
    __syncthreads();
    if (t < 256){
      float us = part[t] + part[t + 256] + bv[c];
      uint32_t p = packsh(us);
      if (!(c & 1)) ((uint32_t*)us4)[c>>1] = p;
    }
    __syncthreads();

    // ---- GRU gates: h=0 -> gx (input us4, W_ih), h=1 -> gh (input hs4, W_hh) ----
    {
      const uint4* IN4 = h ? hs4 : us4;
      const uint4* WP = h ? WHHp4 : WIHp4;
      float a0 = 0.f, a1 = 0.f, a2 = 0.f;
      #pragma unroll 8
      for (int e4 = 0; e4 < 32; ++e4){
        uint4 x = IN4[e4];
        a0 = dot4(x, WP[e4*768 + c], a0);
        a1 = dot4(x, WP[e4*768 + 256 + c], a1);
        a2 = dot4(x, WP[e4*768 + 512 + c], a2);
      }
      float* OUT = h ? gh : gx;
      OUT[c] = a0; OUT[256 + c] = a1; OUT[512 + c] = a2;
    }
    __syncthreads();

    // ---- gate math + LN_m (t<256) ----
    if (t < 256){
      float xr = gx[c]     + bih[c];
      float xz = gx[256+c] + bih[256+c];
      float xn = gx[512+c] + bih[512+c];
      float hr = gh[c]     + bhh[c];
      float hz = gh[256+c] + bhh[256+c];
      float hn = gh[512+c] + bhh[512+c];
      float rg = 1.f/(1.f + __expf(-(xr + hr)));
      float zg = 1.f/(1.f + __expf(-(xz + hz)));
      float ng = tanhf(xn + rg*hn);
      spv = (1.f - zg)*ng + zg*hv;
      float a = wsum64(spv), bs = wsum64(spv*spv);
      if (lane == 0){ redA[w8] = a; redB[w8] = bs; }
    }
    __syncthreads();
    {
      float s1 = redA[0]+redA[1]+redA[2]+redA[3];
      float s2 = redB[0]+redB[1]+redB[2]+redB[3];
      float m = s1*(1.f/256.f), var = s2*(1.f/256.f) - m*m;
      float rstd = rsqrtf(var + 1e-5f);
      if (t < 256){
        float slv = (spv - m)*rstd*lmg[c] + lmb[c];
        uint32_t p = packsh(slv);
        if (!(c & 1)) ((uint32_t*)sln4)[c>>1] = p;
      }
    }
    __syncthreads();

    // ---- hmlp = relu(sln @ w1^T + b1): col = t (0..511) ----
    {
      float a = 0.f;
      #pragma unroll 8
      for (int e4 = 0; e4 < 32; ++e4)
        a = dot4(sln4[e4], W1p4[e4*512 + t], a);
      float hval = fmaxf(a + b1[t], 0.f);
      float o = __shfl_xor(hval, 1);
      if (!(t & 1)) ((uint32_t*)hb4)[t>>1] = pack2h(hval, o);
    }
    __syncthreads();

    // ---- slots = smid + h @ w2^T + b2 : K=512, K-split by h ----
    {
      float a = 0.f;
      #pragma unroll 8
      for (int e4 = h*32; e4 < h*32 + 32; ++e4)
        a = dot4(hb4[e4], W2p4[e4*256 + c], a);
      part[t] = a;
    }
    __syncthreads();
    if (t < 256){
      snv = spv + part[t] + part[t + 256] + b2[c];
      S0[r*256 + c] = snv;
    }
  }

  if (MODE != 2){
    // ---- LN_s(new slots) ----
    if (t < 256){
      float a = wsum64(snv), bs = wsum64(snv*snv);
      if (lane == 0){ redA[w8] = a; redB[w8] = bs; }
    }
    __syncthreads();
    {
      float s1 = redA[0]+redA[1]+redA[2]+redA[3];
      float s2 = redB[0]+redB[1]+redB[2]+redB[3];
      float m = s1*(1.f/256.f), var = s2*(1.f/256.f) - m*m;
      float rstd = rsqrtf(var + 1e-5f);
      if (t < 256){
        float slv = (snv - m)*rstd*lsg[c] + lsb[c];
        uint32_t p = packsh(slv);
        if (!(c & 1)) ((uint32_t*)sln4)[c>>1] = p;
      }
    }
    __syncthreads();

    // ---- q = slnS @ wq^T + bq : K-split by h ----
    {
      float a = 0.f;
      #pragma unroll 8
      for (int e4 = h*16; e4 < h*16 + 16; ++e4)
        a = dot4(sln4[e4], WQp4[e4*256 + c], a);
      part[t] = a;
    }
    __syncthreads();
    if (t < 256){
      float qv = part[t] + part[t + 256] + bq[c];
      float p = wsum64(bk[c] * qv);
      if (lane == 0) redA[w8] = p;
      uint32_t pk = packsh(qv);
      if (!(c & 1)) ((uint32_t*)q4)[c>>1] = pk;
    }
    __syncthreads();
    {
      float cv = redA[0]+redA[1]+redA[2]+redA[3];
      if (t == 0) CV[r] = cv;
    }

    // ---- qt = q @ wk : K-split by h ----
    {
      float a = 0.f;
      #pragma unroll 8
      for (int e4 = h*16; e4 < h*16 + 16; ++e4)
        a = dot4(q4[e4], WKp4[e4*256 + c], a);
      part[t] = a;
    }
    __syncthreads();
    if (t < 256){
      float qtv = part[t] + part[t + 256];
      uint32_t p = packsh(qtv);
      if (!(c & 1)) QTH[b*1024 + (c>>1)*8 + s] = p;
      uacc_z[r*256 + c] = 0.f;
    }
    if (t == 0) asum_z[r] = 0.f;
  }
}

// ---------------- fused attention pass ----------------
// grid (16,32): chunk, b. 256 rows/block in 4 subtiles of 64.
template<bool LAST>
__global__ __launch_bounds__(256) void k_attn(
  const uint32_t* __restrict__ xhat,
  const uint32_t* __restrict__ qtpk, const float* __restrict__ cvec,
  float* __restrict__ uacc, float* __restrict__ asum,
  float* __restrict__ attn_out)
{
  __shared__ uint32_t xs[64*135];
  __shared__ float lg[64*12];
  __shared__ uint32_t qs[1024];
  __shared__ float cs[8];
  const int b = blockIdx.y, chunk = blockIdx.x;
  const int t = threadIdx.x;
  const int lane = t & 63, w = t >> 6;
  for (int i = t; i < 1024; i += 256) qs[i] = qtpk[b*1024 + i];
  if (t < 8) cs[t] = cvec[b*8 + t];
  float up[8] = {0,0,0,0,0,0,0,0};
  float asl[8] = {0,0,0,0,0,0,0,0};
  const int shf = (t & 1) * 16;
  for (int st = 0; st < 4; ++st){
    const int gr0 = b*4096 + chunk*256 + st*64;
    __syncthreads();
    #pragma unroll
    for (int k = 0; k < 8; ++k){
      int c4 = k*256 + t;
      int row = c4 >> 5, j = c4 & 31;
      uint4 dv = ((const uint4*)xhat)[(size_t)(gr0 + row)*32 + j];
      uint32_t* dst = xs + row*135 + j*4;
      dst[0] = dv.x; dst[1] = dv.y; dst[2] = dv.z; dst[3] = dv.w;
    }
    __syncthreads();
    {
      const int s0 = w*2;
      float d0 = 0.f, d1 = 0.f;
      const uint32_t* xr = xs + lane*135;
      #pragma unroll
      for (int dp = 0; dp < 128; ++dp){
        uint32_t x = xr[dp];
        uint2 q = *(const uint2*)(qs + dp*8 + s0);
        d0 = fdot2u(x, q.x, d0);
        d1 = fdot2u(x, q.y, d1);
      }
      *(float2*)(lg + lane*12 + s0) = make_float2(d0, d1);
    }
    __syncthreads();
    if (t < 64){
      float l[8];
      float4 a = *(const float4*)(lg + t*12);
      float4 b4 = *(const float4*)(lg + t*12 + 4);
      l[0]=a.x; l[1]=a.y; l[2]=a.z; l[3]=a.w;
      l[4]=b4.x; l[5]=b4.y; l[6]=b4.z; l[7]=b4.w;
      #pragma unroll
      for (int s = 0; s < 8; ++s) l[s] = (l[s] + cs[s]) * 0.0625f;
      float mx = l[0];
      #pragma unroll
      for (int s = 1; s < 8; ++s) mx = fmaxf(mx, l[s]);
      float sum = 0.f;
      #pragma unroll
      for (int s = 0; s < 8; ++s){ l[s] = __expf(l[s] - mx); sum += l[s]; }
      float inv = 1.0f / sum;
      #pragma unroll
      for (int s = 0; s < 8; ++s){ l[s] = l[s]*inv + 1e-8f; asl[s] += l[s]; }
      float4 o0 = make_float4(l[0], l[1], l[2], l[3]);
      float4 o1 = make_float4(l[4], l[5], l[6], l[7]);
      *(float4*)(lg + t*12) = o0;
      *(float4*)(lg + t*12 + 4) = o1;
      if (LAST){
        float4* ap = (float4*)(attn_out + (size_t)(gr0 + t)*8);
        ap[0] = o0; ap[1] = o1;
      }
    }
    __syncthreads();
    {
      const uint32_t* xc = xs + (t >> 1);
      #pragma unroll 8
      for (int r = 0; r < 64; ++r){
        uint32_t u = xc[r*135];
        float x = __half2float(__ushort_as_half((unsigned short)(u >> shf)));
        float4 a0 = *(const float4*)(lg + r*12);
        float4 a1 = *(const float4*)(lg + r*12 + 4);
        up[0] += a0.x*x; up[1] += a0.y*x; up[2] += a0.z*x; up[3] += a0.w*x;
        up[4] += a1.x*x; up[5] += a1.y*x; up[6] += a1.z*x; up[7] += a1.w*x;
      }
    }
  }
  #pragma unroll
  for (int s = 0; s < 8; ++s) atomicAdd(&uacc[(b*8 + s)*256 + t], up[s]);
  if (t < 64){
    #pragma unroll
    for (int s = 0; s < 8; ++s){
      float v = wsum64(asl[s]);
      if (t == 0) atomicAdd(&asum[b*8 + s], v);
    }
  }
}

// ---------------- final output: slots copy + attn renormalize ----------------
__global__ __launch_bounds__(256) void k_out(
  const float* __restrict__ S0, const float* __restrict__ asum,
  float* __restrict__ out)
{
  int i = blockIdx.x * 256 + threadIdx.x;
  if (i < 65536) out[i] = S0[i];
  else {
    int j = i - 65536;
    int b = j >> 15;
    int s = j & 7;
    out[i] = out[i] * (1.0f / asum[b*8 + s]);
  }
}

extern "C" void kernel_launch(void* const* d_in, const int* in_sizes, int n_in,
                              void* d_out, int out_size, void* d_ws, size_t ws_size,
                              hipStream_t stream) {
  const float* inputs = (const float*)d_in[0];
  const float* noise  = (const float*)d_in[1];
  const float* mu     = (const float*)d_in[2];
  const float* sigraw = (const float*)d_in[3];
  const float* lng    = (const float*)d_in[4];
  const float* lnb    = (const float*)d_in[5];
  const float* lsg    = (const float*)d_in[6];
  const float* lsb    = (const float*)d_in[7];
  const float* lmg    = (const float*)d_in[8];
  const float* lmb    = (const float*)d_in[9];
  const float* wq     = (const float*)d_in[10];
  const float* bq     = (const float*)d_in[11];
  const float* wk     = (const float*)d_in[12];
  const float* bk     = (const float*)d_in[13];
  const float* wv     = (const float*)d_in[14];
  const float* bv     = (const float*)d_in[15];
  const float* wih    = (const float*)d_in[16];
  const float* whh    = (const float*)d_in[17];
  const float* bih    = (const float*)d_in[18];
  const float* bhh    = (const float*)d_in[19];
  const float* w1     = (const float*)d_in[20];
  const float* b1     = (const float*)d_in[21];
  const float* w2     = (const float*)d_in[22];
  const float* b2     = (const float*)d_in[23];
  float* out = (float*)d_out;

  char* w = (char*)d_ws;
  size_t o = 0;
  uint32_t* XH = (uint32_t*)w;  o += 67108864;
  uint32_t* QT = (uint32_t*)(w + o); o += 131072;
  float* CV  = (float*)(w + o); o += 1024;
  float* UA  = (float*)(w + o); o += 262144;
  float* AS  = (float*)(w + o); o += 1024;
  float* S0  = (float*)(w + o); o += 262144;
  uint4* WQp = (uint4*)(w + o); o += 131072;
  uint4* WVp = (uint4*)(w + o); o += 131072;
  uint4* WIHp= (uint4*)(w + o); o += 393216;
  uint4* WHHp= (uint4*)(w + o); o += 393216;
  uint4* W1p = (uint4*)(w + o); o += 262144;
  uint4* W2p = (uint4*)(w + o); o += 262144;
  uint4* WKp = (uint4*)(w + o); o += 131072;

  k_tr<<<416, 256, 0, stream>>>(wq, wv, wih, whh, w1, w2, wk,
                                WQp, WVp, WIHp, WHHp, W1p, W2p, WKp);
  k_ln<<<32768, 256, 0, stream>>>(inputs, lng, lnb, XH);
  k_slot<0><<<256, 512, 0, stream>>>(noise, mu, sigraw, S0, UA, AS,
      WVp, bv, WIHp, WHHp, bih, bhh, lmg, lmb, W1p, b1, W2p, b2,
      lsg, lsb, WQp, bq, WKp, bk, QT, CV, UA, AS);

  dim3 ga(16, 32);
  for (int it = 0; it < 3; ++it){
    if (it == 2) k_attn<true ><<<ga, 256, 0, stream>>>(XH, QT, CV, UA, AS, out + 65536);
    else         k_attn<false><<<ga, 256, 0, stream>>>(XH, QT, CV, UA, AS, out + 65536);
    if (it < 2)
      k_slot<1><<<256, 512, 0, stream>>>(noise, mu, sigraw, S0, UA, AS,
          WVp, bv, WIHp, WHHp, bih, bhh, lmg, lmb, W1p, b1, W2p, b2,
          lsg, lsb, WQp, bq, WKp, bk, QT, CV, UA, AS);
    else
      k_slot<2><<<256, 512, 0, stream>>>(noise, mu, sigraw, S0, UA, AS,
          WVp, bv, WIHp, WHHp, bih, bhh, lmg, lmb, W1p, b1, W2p, b2,
          lsg, lsb, WQp, bq, WKp, bk, QT, CV, UA, AS);
  }
  k_out<<<4352, 256, 0, stream>>>(S0, AS, out);
}